// Round 9
// baseline (1080.016 us; speedup 1.0000x reference)
//
#include <hip/hip_runtime.h>

// ---------------------------------------------------------------------------
// Round 13: R10 skeleton (best: 899.7us) + A-fragment register roll for
// dilation-1 layers. R12 post-mortem: XCD swizzle cut gconv FETCH 160->100MB
// with NO dur gain and a net regression -> big layers are LDS-pipe-bound,
// not memory-bound; swizzle reverted.
// New here (non-gconv conv_mfma only, barrier skeleton untouched):
//   chunk(mt, ky+1, kx) == chunk(mt+1, ky, kx) for d=1, so A-fragments roll
//   through registers across the 3 tap-rows of each cb: 12 fresh ds_reads at
//   ky=-1, then 3 per tap-row (AF[j][0..2] <- AF[j][1..3], fresh AF[j][3]).
//   A reads/cb 36 -> 18; total LDS reads/cb 72 -> 54 (-25%).
// Gconv layers byte-identical to R10 (per-row masks break the identity).
// ---------------------------------------------------------------------------

typedef __attribute__((ext_vector_type(8))) short short8;
typedef __attribute__((ext_vector_type(4))) float f32x4;

__device__ __forceinline__ float b2f(ushort u) {
    return __uint_as_float(((unsigned)u) << 16);
}
__device__ __forceinline__ ushort f2b(float f) {   // round-to-nearest-even
    unsigned x = __float_as_uint(f);
    x += 0x7FFFu + ((x >> 16) & 1u);
    return (ushort)(x >> 16);
}
__device__ __forceinline__ float fmaxf2(float a, float b) { return a > b ? a : b; }

// ---- repack weights [co][ci][t] f32 -> [t][cb][q][co][ci8] bf16, all layers
struct RepackArgs {
    const float* w[9];
    ushort*      wp[9];
    int cin[9];
    int cout[9];
    int off[10];        // elem-count prefix sums, off[9] = total
};

__global__ __launch_bounds__(256)
void repack_all(RepackArgs a)
{
    int i = blockIdx.x * 256 + threadIdx.x;
    if (i >= a.off[9]) return;
    int l = 0;
    #pragma unroll
    for (int k = 1; k < 9; ++k) l += (i >= a.off[k]);
    int j = i - a.off[l];
    int Cin = a.cin[l], Cout = a.cout[l];
    int CBl  = Cin / 32;
    int c8   = j & 7;
    int co   = (j >> 3) % Cout;          // Cout is a power of two
    int rest = (j >> 3) / Cout;          // = (t*CBl + cb)*4 + q
    int q    = rest & 3;
    int cbt  = rest >> 2;
    int cb   = cbt % CBl;
    int t    = cbt / CBl;
    int ci   = cb * 32 + q * 8 + c8;
    a.wp[l][j] = f2b(a.w[l][((size_t)co * Cin + ci) * 9 + t]);
}

// ------------- L1: 3->64 direct conv, fp32 NCHW in -> bf16 NHWC out ---------
__global__ __launch_bounds__(256)
void l1_conv(const float* __restrict__ in, const float* __restrict__ w,
             const float* __restrict__ bias, ushort* __restrict__ out)
{
    const int H = 384, W = 384;
    __shared__ float s[3][18][18];
    const int tid = threadIdx.x;
    const int tilesX = W / 16;
    const int x0 = (blockIdx.x % tilesX) * 16;
    const int y0 = (blockIdx.x / tilesX) * 16;
    const int b  = blockIdx.z;

    for (int i = tid; i < 3 * 18 * 18; i += 256) {
        int ci = i / (18 * 18);
        int r  = i % (18 * 18);
        int iy = r / 18, ix = r % 18;
        int gy = y0 - 1 + iy, gx = x0 - 1 + ix;
        float v = 0.f;
        if ((unsigned)gy < (unsigned)H && (unsigned)gx < (unsigned)W)
            v = in[((size_t)(b * 3 + ci) * H + gy) * W + gx];
        s[ci][iy][ix] = v;
    }
    __syncthreads();

    const int tx = tid & 15, ty = tid >> 4;
    float iv[3][3][3];
    #pragma unroll
    for (int ci = 0; ci < 3; ++ci)
        #pragma unroll
        for (int ky = 0; ky < 3; ++ky)
            #pragma unroll
            for (int kx = 0; kx < 3; ++kx)
                iv[ci][ky][kx] = s[ci][ty + ky][tx + kx];

    size_t pix = ((size_t)(b * H + y0 + ty) * W + x0 + tx);
    #pragma unroll
    for (int c4 = 0; c4 < 4; ++c4) {
        __align__(16) ushort ob[16];
        #pragma unroll
        for (int co = 0; co < 16; ++co) {
            int coG = c4 * 16 + co;
            float a = bias[coG];
            #pragma unroll
            for (int ci = 0; ci < 3; ++ci)
                #pragma unroll
                for (int ky = 0; ky < 3; ++ky)
                    #pragma unroll
                    for (int kx = 0; kx < 3; ++kx)
                        a = fmaf(w[((size_t)coG * 3 + ci) * 9 + ky * 3 + kx],
                                 iv[ci][ky][kx], a);
            a = a > 0.f ? a : 0.f;
            ob[co] = f2b(a);
        }
        *(short8*)&out[pix * 64 + c4 * 16]     = *(short8*)&ob[0];
        *(short8*)&out[pix * 64 + c4 * 16 + 8] = *(short8*)&ob[8];
    }
}

// ------------- implicit-GEMM conv3x3, tap-row staged, bf16 MFMA -------------
// Block = TRx16 output pixels, 256 threads = 4 waves, wave tile 64x64.
// Per cb: A halo staged once; B staged per tap-ROW with register prefetch of
// next row's B / next cb's A before the MFMA section. Conflict-free LDS
// layouts (sA q-plane-major stride NCH+2; sB [tap][q][co] wave-linear).
// Non-gconv: A-fragments ROLL through registers across the 3 tap-rows
// (d=1 identity chunk(mt,ky+1)=chunk(mt+1,ky)): 12+3+3 A reads/cb vs 36.
// POOL: 0=none, 1=fused 2x2 maxpool (halved output), 2=fused irregular pool.
template<int TR, int BN, int CIN, int COUT, int H, int W, bool GCONV, bool FINAL,
         int POOL>
__global__ __launch_bounds__(256)
void conv_mfma(const ushort* __restrict__ in, const ushort* __restrict__ wp,
               const float* __restrict__ bias, void* __restrict__ outv,
               const int* __restrict__ mask)
{
    constexpr int BM   = TR * 16;
    constexpr int CB   = CIN / 32;
    constexpr int HA   = GCONV ? 2 : 1;
    constexpr int CW   = 16 + 2 * HA;
    constexpr int CR   = TR + 2 * HA;
    constexpr int NCH  = CR * CW;            // A chunks (pixels) per cb
    constexpr int NCHP = NCH + 2;            // q-plane stride (de-alias stores)
    constexpr int WM   = BM / 64;
    constexpr int NSA  = NCH * 4;            // 16B units to stage for A
    constexpr int NSLA = (NSA + 255) / 256;
    constexpr int NSB  = 12 * BN;            // 16B units per tap-row of B
    constexpr int NSLB = NSB / 256;
    static_assert(NSB % 256 == 0, "B staging must tile 256 threads");

    __shared__ __align__(16) ushort sA[4 * NCHP * 8];
    __shared__ __align__(16) ushort sB[12 * BN * 8];

    const int tid  = threadIdx.x;
    const int lane = tid & 63;
    const int wv   = tid >> 6;
    const int wm   = wv % WM;
    const int wn   = wv / WM;
    const int col  = lane & 15;
    const int quad = lane >> 4;

    const int tiles_x = W / 16, tiles_y = H / TR;
    int sp = blockIdx.x;
    const int b  = sp / (tiles_x * tiles_y);
    int rr = sp - b * tiles_x * tiles_y;
    const int ty = rr / tiles_x;
    const int tx = rr - ty * tiles_x;
    const int y0 = ty * TR, x0 = tx * 16;
    const int co0 = blockIdx.y * BN;

    int dA[4], aoff[4];
    #pragma unroll
    for (int mt = 0; mt < 4; ++mt) {
        dA[mt] = 1;
        if (GCONV) {
            int y = y0 + wm * 4 + mt, x = x0 + col;
            dA[mt] = mask[(b * (H / 2) + (y >> 1)) * (W / 2) + (x >> 1)] ? 2 : 1;
        }
        aoff[mt] = (HA + wm * 4 + mt) * CW + HA + col;
    }

    short8 pA[NSLA];
    short8 pB[NSLB];

    auto loadA = [&](int cb) {
        #pragma unroll
        for (int k = 0; k < NSLA; ++k) {
            int i = tid + k * 256;
            short8 v = {0, 0, 0, 0, 0, 0, 0, 0};
            if (NSA == NSLA * 256 || i < NSA) {
                int chunk = i >> 2, part = i & 3;     // coalesced: 64B / 4 lanes
                int yy = chunk / CW, xx = chunk - yy * CW;
                int gy = y0 - HA + yy, gx = x0 - HA + xx;
                if ((unsigned)gy < (unsigned)H && (unsigned)gx < (unsigned)W)
                    v = *(const short8*)(in + ((size_t)(b * H + gy) * W + gx) * CIN
                                         + cb * 32 + part * 8);
            }
            pA[k] = v;
        }
    };
    auto storeA = [&]() {
        #pragma unroll
        for (int k = 0; k < NSLA; ++k) {
            int i = tid + k * 256;
            if (NSA == NSLA * 256 || i < NSA) {
                int chunk = i >> 2, part = i & 3;
                *(short8*)&sA[(part * NCHP + chunk) * 8] = pA[k];
            }
        }
    };
    auto loadB = [&](int s) {
        int cb = s / 3, row = s % 3;
        #pragma unroll
        for (int k = 0; k < NSLB; ++k) {
            int i = tid + k * 256;
            int co = i % BN;
            int rq = i / BN;                     // tl*4 + q
            const ushort* gp = wp
                + (((size_t)(row * 3 + (rq >> 2)) * CB + cb) * 4 + (rq & 3))
                      * COUT * 8
                + (size_t)(co0 + co) * 8;
            pB[k] = *(const short8*)gp;          // wave reads 1KB contiguous
        }
    };
    auto storeB = [&]() {
        #pragma unroll
        for (int k = 0; k < NSLB; ++k) {
            int i = tid + k * 256;
            *(short8*)&sB[(size_t)i * 8] = pB[k];    // wave-linear, 0 conflicts
        }
    };

    f32x4 acc[4][4];
    #pragma unroll
    for (int i = 0; i < 4; ++i)
        #pragma unroll
        for (int j = 0; j < 4; ++j)
            acc[i][j] = (f32x4){0.f, 0.f, 0.f, 0.f};

    // prologue
    loadA(0);
    loadB(0);
    storeA();
    storeB();
    __syncthreads();

    short8 AF[3][4];   // non-gconv: rolled A-fragments [kx][mt]

    for (int cb = 0; cb < CB; ++cb) {
        #pragma unroll
        for (int row = 0; row < 3; ++row) {
            const int s = cb * 3 + row;
            const bool last = (s == 3 * CB - 1);
            if (!last) {
                loadB(s + 1);                 // global prefetch, lands at storeB
                if (row == 2) loadA(cb + 1);
            }
            const int ky = row - 1;
            if (!GCONV) {
                // ---- A-fragment roll (d == 1) ----
                if (row == 0) {
                    #pragma unroll
                    for (int j = 0; j < 3; ++j)
                        #pragma unroll
                        for (int i = 0; i < 4; ++i)
                            AF[j][i] = *(const short8*)&sA[
                                (quad * NCHP + aoff[i] + (ky * CW + j - 1)) * 8];
                } else {
                    #pragma unroll
                    for (int j = 0; j < 3; ++j) {
                        AF[j][0] = AF[j][1];
                        AF[j][1] = AF[j][2];
                        AF[j][2] = AF[j][3];
                        AF[j][3] = *(const short8*)&sA[
                            (quad * NCHP + aoff[3] + (ky * CW + j - 1)) * 8];
                    }
                }
                #pragma unroll
                for (int j = 0; j < 3; ++j) {
                    short8 bf4[4];
                    #pragma unroll
                    for (int i = 0; i < 4; ++i)
                        bf4[i] = *(const short8*)&sB[((j * 4 + quad) * BN
                                                      + wn * 64 + i * 16 + col) * 8];
                    #pragma unroll
                    for (int mt = 0; mt < 4; ++mt)
                        #pragma unroll
                        for (int nt = 0; nt < 4; ++nt)
                            acc[mt][nt] = __builtin_amdgcn_mfma_f32_16x16x32_bf16(
                                AF[j][mt], bf4[nt], acc[mt][nt], 0, 0, 0);
                }
            } else {
                // ---- gconv path: byte-identical to R10 ----
                #pragma unroll
                for (int j = 0; j < 3; ++j) {
                    const int kx = j - 1;
                    short8 af[4], bf4[4];
                    #pragma unroll
                    for (int i = 0; i < 4; ++i) {
                        int chunk = aoff[i] + dA[i] * (ky * CW + kx);
                        af[i]  = *(const short8*)&sA[(quad * NCHP + chunk) * 8];
                        bf4[i] = *(const short8*)&sB[((j * 4 + quad) * BN
                                                      + wn * 64 + i * 16 + col) * 8];
                    }
                    #pragma unroll
                    for (int mt = 0; mt < 4; ++mt)
                        #pragma unroll
                        for (int nt = 0; nt < 4; ++nt)
                            acc[mt][nt] = __builtin_amdgcn_mfma_f32_16x16x32_bf16(
                                af[mt], bf4[nt], acc[mt][nt], 0, 0, 0);
                }
            }
            if (!last) {
                __syncthreads();              // all reads of sA/sB done
                storeB();
                if (row == 2) storeA();
                __syncthreads();              // writes visible
            }
        }
    }

    // ---- epilogue ----
    if (FINAL) {
        float* outp = (float*)outv;   // fp32 NCHW direct to d_out
        #pragma unroll
        for (int mt = 0; mt < 4; ++mt) {
            int y = y0 + wm * 4 + mt;
            #pragma unroll
            for (int nt = 0; nt < 4; ++nt) {
                int co = co0 + wn * 64 + nt * 16 + col;
                float bv = bias[co];
                f32x4 vv;
                #pragma unroll
                for (int r2 = 0; r2 < 4; ++r2) {
                    float z = acc[mt][nt][r2] + bv;
                    vv[r2] = z > 0.f ? z : 0.f;
                }
                *(f32x4*)&outp[((size_t)(b * COUT + co) * H + y) * W + x0 + quad * 4] = vv;
            }
        }
    } else if (POOL == 0) {
        ushort* outp = (ushort*)outv;
        #pragma unroll
        for (int mt = 0; mt < 4; ++mt) {
            int y = y0 + wm * 4 + mt;
            #pragma unroll
            for (int nt = 0; nt < 4; ++nt) {
                int co = co0 + wn * 64 + nt * 16 + col;
                float bv = bias[co];
                #pragma unroll
                for (int r2 = 0; r2 < 4; ++r2) {
                    int x = x0 + quad * 4 + r2;
                    float vv = acc[mt][nt][r2] + bv;
                    vv = vv > 0.f ? vv : 0.f;
                    outp[((size_t)(b * H + y) * W + x) * COUT + co] = f2b(vv);
                }
            }
        }
    } else if (POOL == 1) {
        // fused 2x2 maxpool: output is (H/2)x(W/2), NHWC bf16.
        // 2x2 windows are thread-local: rows (wm*4+2*mt2, +1), cols (quad*4+2j, +1).
        ushort* outp = (ushort*)outv;
        #pragma unroll
        for (int nt = 0; nt < 4; ++nt) {
            int co = co0 + wn * 64 + nt * 16 + col;
            float bv = bias[co];
            float v[4][4];
            #pragma unroll
            for (int mt = 0; mt < 4; ++mt)
                #pragma unroll
                for (int r2 = 0; r2 < 4; ++r2) {
                    float z = acc[mt][nt][r2] + bv;
                    v[mt][r2] = z > 0.f ? z : 0.f;
                }
            #pragma unroll
            for (int mt2 = 0; mt2 < 2; ++mt2) {
                int yp = (y0 >> 1) + wm * 2 + mt2;
                #pragma unroll
                for (int j = 0; j < 2; ++j) {
                    int xp = (x0 >> 1) + quad * 2 + j;
                    float m = fmaxf2(fmaxf2(v[2*mt2][2*j],   v[2*mt2][2*j+1]),
                                     fmaxf2(v[2*mt2+1][2*j], v[2*mt2+1][2*j+1]));
                    outp[((size_t)(b * (H/2) + yp) * (W/2) + xp) * COUT + co] = f2b(m);
                }
            }
        }
    } else {
        // POOL == 2: fused irregular pool (mask-gated 2x2 max, replicated).
        ushort* outp = (ushort*)outv;
        int mc[2][2];
        #pragma unroll
        for (int my = 0; my < 2; ++my)
            #pragma unroll
            for (int mx = 0; mx < 2; ++mx) {
                int y = y0 + wm * 4 + my * 2;
                int x = x0 + quad * 4 + mx * 2;
                mc[my][mx] = mask[(b * (H / 2) + (y >> 1)) * (W / 2) + (x >> 1)];
            }
        #pragma unroll
        for (int nt = 0; nt < 4; ++nt) {
            int co = co0 + wn * 64 + nt * 16 + col;
            float bv = bias[co];
            float v[4][4];
            #pragma unroll
            for (int mt = 0; mt < 4; ++mt)
                #pragma unroll
                for (int r2 = 0; r2 < 4; ++r2) {
                    float z = acc[mt][nt][r2] + bv;
                    v[mt][r2] = z > 0.f ? z : 0.f;
                }
            #pragma unroll
            for (int mt = 0; mt < 4; ++mt) {
                int y = y0 + wm * 4 + mt;
                #pragma unroll
                for (int r2 = 0; r2 < 4; ++r2) {
                    int x = x0 + quad * 4 + r2;
                    float p = fmaxf2(fmaxf2(v[mt][r2],     v[mt][r2 ^ 1]),
                                     fmaxf2(v[mt ^ 1][r2], v[mt ^ 1][r2 ^ 1]));
                    float o = mc[mt >> 1][r2 >> 1] ? p : v[mt][r2];
                    outp[((size_t)(b * H + y) * W + x) * COUT + co] = f2b(o);
                }
            }
        }
    }
}

// ---------------------------------------------------------------------------
extern "C" void kernel_launch(void* const* d_in, const int* in_sizes, int n_in,
                              void* d_out, int out_size, void* d_ws, size_t ws_size,
                              hipStream_t stream)
{
    const float* x    = (const float*)d_in[0];
    const int*   mask = (const int*)d_in[1];
    const float* Wt[10];
    const float* bs[10];
    for (int i = 0; i < 10; ++i) {
        Wt[i] = (const float*)d_in[2 + 2 * i];
        bs[i] = (const float*)d_in[3 + 2 * i];
    }

    const size_t ACT = (size_t)4 * 384 * 384 * 64;   // ushorts
    ushort* A  = (ushort*)d_ws;
    ushort* Bb = A + ACT;
    ushort* wpbase = Bb + ACT;

    static const int cins[10]  = {3, 64, 64, 128, 128, 256, 256, 256, 512, 512};
    static const int couts[10] = {64, 64, 128, 128, 256, 256, 256, 512, 512, 512};
    ushort* wp[10];
    size_t wo = 0;
    for (int l = 1; l < 10; ++l) {
        wp[l] = wpbase + wo;
        wo += (size_t)couts[l] * cins[l] * 9;
    }

    RepackArgs ra;
    int off = 0;
    for (int l = 1; l < 10; ++l) {
        ra.w[l - 1]    = Wt[l];
        ra.wp[l - 1]   = wp[l];
        ra.cin[l - 1]  = cins[l];
        ra.cout[l - 1] = couts[l];
        ra.off[l - 1]  = off;
        off += couts[l] * cins[l] * 9;
    }
    ra.off[9] = off;
    repack_all<<<(off + 255) / 256, 256, 0, stream>>>(ra);

    // L1: fp32 NCHW -> bf16 NHWC
    l1_conv<<<dim3(24 * 24, 1, 4), 256, 0, stream>>>(x, Wt[0], bs[0], A);

    // L2: 64->64 @384 (tile 16x16, BN=64), fused maxpool -> 192^2
    conv_mfma<16, 64, 64, 64, 384, 384, false, false, 1>
        <<<dim3(4 * 24 * 24, 1), 256, 0, stream>>>(A, wp[1], bs[1], Bb, nullptr);

    // L3: 64->128 @192 (tile 8x16, BN=128)
    conv_mfma<8, 128, 64, 128, 192, 192, false, false, 0>
        <<<dim3(4 * 24 * 12, 1), 256, 0, stream>>>(Bb, wp[2], bs[2], A, nullptr);
    // L4: 128->128 @192, fused maxpool -> 96^2
    conv_mfma<8, 128, 128, 128, 192, 192, false, false, 1>
        <<<dim3(4 * 24 * 12, 1), 256, 0, stream>>>(A, wp[3], bs[3], Bb, nullptr);

    // L5: 128->256 @96
    conv_mfma<8, 128, 128, 256, 96, 96, false, false, 0>
        <<<dim3(4 * 12 * 6, 2), 256, 0, stream>>>(Bb, wp[4], bs[4], A, nullptr);
    // L6: 256->256
    conv_mfma<8, 128, 256, 256, 96, 96, false, false, 0>
        <<<dim3(4 * 12 * 6, 2), 256, 0, stream>>>(A, wp[5], bs[5], Bb, nullptr);
    // L7: 256->256, fused irregular pool
    conv_mfma<8, 128, 256, 256, 96, 96, false, false, 2>
        <<<dim3(4 * 12 * 6, 2), 256, 0, stream>>>(Bb, wp[6], bs[6], A, mask);

    // L8: gconv 256->512
    conv_mfma<8, 128, 256, 512, 96, 96, true, false, 0>
        <<<dim3(4 * 12 * 6, 4), 256, 0, stream>>>(A, wp[7], bs[7], Bb, mask);
    // L9: gconv 512->512
    conv_mfma<8, 128, 512, 512, 96, 96, true, false, 0>
        <<<dim3(4 * 12 * 6, 4), 256, 0, stream>>>(Bb, wp[8], bs[8], A, mask);
    // L10: gconv 512->512 -> fp32 NCHW d_out
    conv_mfma<8, 128, 512, 512, 96, 96, true, true, 0>
        <<<dim3(4 * 12 * 6, 4), 256, 0, stream>>>(A, wp[9], bs[9], d_out, mask);

    (void)in_sizes; (void)n_in; (void)out_size; (void)ws_size;
}

// Round 10
// 938.011 us; speedup vs baseline: 1.1514x; 1.1514x over previous
//
#include <hip/hip_runtime.h>

// ---------------------------------------------------------------------------
// Round 14: compose R10-gconv + R13-nongconv.
// R13 post-mortem: wrapping BOTH paths in the unrolled 3-row loop pushed the
// gconv instantiations to VGPR 136 (occupancy 18->10.5%, 190->275us/dispatch)
// BUT the net math shows non-gconv layers got ~115us FASTER from the A-roll
// (-25% LDS reads confirmed). So: if constexpr(GCONV) -> R10's runtime
// s-loop verbatim (VGPR 104); else -> R13's unrolled cb/row loop with the
// AF register roll. Pure recombination of the two measured bests.
// ---------------------------------------------------------------------------

typedef __attribute__((ext_vector_type(8))) short short8;
typedef __attribute__((ext_vector_type(4))) float f32x4;

__device__ __forceinline__ float b2f(ushort u) {
    return __uint_as_float(((unsigned)u) << 16);
}
__device__ __forceinline__ ushort f2b(float f) {   // round-to-nearest-even
    unsigned x = __float_as_uint(f);
    x += 0x7FFFu + ((x >> 16) & 1u);
    return (ushort)(x >> 16);
}
__device__ __forceinline__ float fmaxf2(float a, float b) { return a > b ? a : b; }

// ---- repack weights [co][ci][t] f32 -> [t][cb][q][co][ci8] bf16, all layers
struct RepackArgs {
    const float* w[9];
    ushort*      wp[9];
    int cin[9];
    int cout[9];
    int off[10];        // elem-count prefix sums, off[9] = total
};

__global__ __launch_bounds__(256)
void repack_all(RepackArgs a)
{
    int i = blockIdx.x * 256 + threadIdx.x;
    if (i >= a.off[9]) return;
    int l = 0;
    #pragma unroll
    for (int k = 1; k < 9; ++k) l += (i >= a.off[k]);
    int j = i - a.off[l];
    int Cin = a.cin[l], Cout = a.cout[l];
    int CBl  = Cin / 32;
    int c8   = j & 7;
    int co   = (j >> 3) % Cout;          // Cout is a power of two
    int rest = (j >> 3) / Cout;          // = (t*CBl + cb)*4 + q
    int q    = rest & 3;
    int cbt  = rest >> 2;
    int cb   = cbt % CBl;
    int t    = cbt / CBl;
    int ci   = cb * 32 + q * 8 + c8;
    a.wp[l][j] = f2b(a.w[l][((size_t)co * Cin + ci) * 9 + t]);
}

// ------------- L1: 3->64 direct conv, fp32 NCHW in -> bf16 NHWC out ---------
__global__ __launch_bounds__(256)
void l1_conv(const float* __restrict__ in, const float* __restrict__ w,
             const float* __restrict__ bias, ushort* __restrict__ out)
{
    const int H = 384, W = 384;
    __shared__ float s[3][18][18];
    const int tid = threadIdx.x;
    const int tilesX = W / 16;
    const int x0 = (blockIdx.x % tilesX) * 16;
    const int y0 = (blockIdx.x / tilesX) * 16;
    const int b  = blockIdx.z;

    for (int i = tid; i < 3 * 18 * 18; i += 256) {
        int ci = i / (18 * 18);
        int r  = i % (18 * 18);
        int iy = r / 18, ix = r % 18;
        int gy = y0 - 1 + iy, gx = x0 - 1 + ix;
        float v = 0.f;
        if ((unsigned)gy < (unsigned)H && (unsigned)gx < (unsigned)W)
            v = in[((size_t)(b * 3 + ci) * H + gy) * W + gx];
        s[ci][iy][ix] = v;
    }
    __syncthreads();

    const int tx = tid & 15, ty = tid >> 4;
    float iv[3][3][3];
    #pragma unroll
    for (int ci = 0; ci < 3; ++ci)
        #pragma unroll
        for (int ky = 0; ky < 3; ++ky)
            #pragma unroll
            for (int kx = 0; kx < 3; ++kx)
                iv[ci][ky][kx] = s[ci][ty + ky][tx + kx];

    size_t pix = ((size_t)(b * H + y0 + ty) * W + x0 + tx);
    #pragma unroll
    for (int c4 = 0; c4 < 4; ++c4) {
        __align__(16) ushort ob[16];
        #pragma unroll
        for (int co = 0; co < 16; ++co) {
            int coG = c4 * 16 + co;
            float a = bias[coG];
            #pragma unroll
            for (int ci = 0; ci < 3; ++ci)
                #pragma unroll
                for (int ky = 0; ky < 3; ++ky)
                    #pragma unroll
                    for (int kx = 0; kx < 3; ++kx)
                        a = fmaf(w[((size_t)coG * 3 + ci) * 9 + ky * 3 + kx],
                                 iv[ci][ky][kx], a);
            a = a > 0.f ? a : 0.f;
            ob[co] = f2b(a);
        }
        *(short8*)&out[pix * 64 + c4 * 16]     = *(short8*)&ob[0];
        *(short8*)&out[pix * 64 + c4 * 16 + 8] = *(short8*)&ob[8];
    }
}

// ------------- implicit-GEMM conv3x3, tap-row staged, bf16 MFMA -------------
// Block = TRx16 output pixels, 256 threads = 4 waves, wave tile 64x64.
// Per cb: A halo staged once; B staged per tap-ROW with register prefetch of
// next row's B / next cb's A before the MFMA section. Conflict-free LDS
// layouts (sA q-plane-major stride NCH+2; sB [tap][q][co] wave-linear).
// GCONV: R10's runtime s-loop (VGPR 104, occupancy-preserving).
// !GCONV: unrolled cb/row loop + A-fragment register roll
//   (d=1 identity chunk(mt,ky+1)=chunk(mt+1,ky)): A reads/cb 36 -> 18.
// POOL: 0=none, 1=fused 2x2 maxpool (halved output), 2=fused irregular pool.
template<int TR, int BN, int CIN, int COUT, int H, int W, bool GCONV, bool FINAL,
         int POOL>
__global__ __launch_bounds__(256)
void conv_mfma(const ushort* __restrict__ in, const ushort* __restrict__ wp,
               const float* __restrict__ bias, void* __restrict__ outv,
               const int* __restrict__ mask)
{
    constexpr int BM   = TR * 16;
    constexpr int CB   = CIN / 32;
    constexpr int HA   = GCONV ? 2 : 1;
    constexpr int CW   = 16 + 2 * HA;
    constexpr int CR   = TR + 2 * HA;
    constexpr int NCH  = CR * CW;            // A chunks (pixels) per cb
    constexpr int NCHP = NCH + 2;            // q-plane stride (de-alias stores)
    constexpr int WM   = BM / 64;
    constexpr int NSA  = NCH * 4;            // 16B units to stage for A
    constexpr int NSLA = (NSA + 255) / 256;
    constexpr int NSB  = 12 * BN;            // 16B units per tap-row of B
    constexpr int NSLB = NSB / 256;
    static_assert(NSB % 256 == 0, "B staging must tile 256 threads");

    __shared__ __align__(16) ushort sA[4 * NCHP * 8];
    __shared__ __align__(16) ushort sB[12 * BN * 8];

    const int tid  = threadIdx.x;
    const int lane = tid & 63;
    const int wv   = tid >> 6;
    const int wm   = wv % WM;
    const int wn   = wv / WM;
    const int col  = lane & 15;
    const int quad = lane >> 4;

    const int tiles_x = W / 16, tiles_y = H / TR;
    int sp = blockIdx.x;
    const int b  = sp / (tiles_x * tiles_y);
    int rr = sp - b * tiles_x * tiles_y;
    const int ty = rr / tiles_x;
    const int tx = rr - ty * tiles_x;
    const int y0 = ty * TR, x0 = tx * 16;
    const int co0 = blockIdx.y * BN;

    int dA[4], aoff[4];
    #pragma unroll
    for (int mt = 0; mt < 4; ++mt) {
        dA[mt] = 1;
        if (GCONV) {
            int y = y0 + wm * 4 + mt, x = x0 + col;
            dA[mt] = mask[(b * (H / 2) + (y >> 1)) * (W / 2) + (x >> 1)] ? 2 : 1;
        }
        aoff[mt] = (HA + wm * 4 + mt) * CW + HA + col;
    }

    short8 pA[NSLA];
    short8 pB[NSLB];

    auto loadA = [&](int cb) {
        #pragma unroll
        for (int k = 0; k < NSLA; ++k) {
            int i = tid + k * 256;
            short8 v = {0, 0, 0, 0, 0, 0, 0, 0};
            if (NSA == NSLA * 256 || i < NSA) {
                int chunk = i >> 2, part = i & 3;     // coalesced: 64B / 4 lanes
                int yy = chunk / CW, xx = chunk - yy * CW;
                int gy = y0 - HA + yy, gx = x0 - HA + xx;
                if ((unsigned)gy < (unsigned)H && (unsigned)gx < (unsigned)W)
                    v = *(const short8*)(in + ((size_t)(b * H + gy) * W + gx) * CIN
                                         + cb * 32 + part * 8);
            }
            pA[k] = v;
        }
    };
    auto storeA = [&]() {
        #pragma unroll
        for (int k = 0; k < NSLA; ++k) {
            int i = tid + k * 256;
            if (NSA == NSLA * 256 || i < NSA) {
                int chunk = i >> 2, part = i & 3;
                *(short8*)&sA[(part * NCHP + chunk) * 8] = pA[k];
            }
        }
    };
    auto loadB = [&](int s) {
        int cb = s / 3, row = s % 3;
        #pragma unroll
        for (int k = 0; k < NSLB; ++k) {
            int i = tid + k * 256;
            int co = i % BN;
            int rq = i / BN;                     // tl*4 + q
            const ushort* gp = wp
                + (((size_t)(row * 3 + (rq >> 2)) * CB + cb) * 4 + (rq & 3))
                      * COUT * 8
                + (size_t)(co0 + co) * 8;
            pB[k] = *(const short8*)gp;          // wave reads 1KB contiguous
        }
    };
    auto storeB = [&]() {
        #pragma unroll
        for (int k = 0; k < NSLB; ++k) {
            int i = tid + k * 256;
            *(short8*)&sB[(size_t)i * 8] = pB[k];    // wave-linear, 0 conflicts
        }
    };

    f32x4 acc[4][4];
    #pragma unroll
    for (int i = 0; i < 4; ++i)
        #pragma unroll
        for (int j = 0; j < 4; ++j)
            acc[i][j] = (f32x4){0.f, 0.f, 0.f, 0.f};

    // prologue
    loadA(0);
    loadB(0);
    storeA();
    storeB();
    __syncthreads();

    if constexpr (GCONV) {
        // ---- R10's loop, verbatim (runtime row; keeps VGPR at 104) ----
        for (int s = 0; s < 3 * CB; ++s) {
            const int row  = s % 3;
            const bool last = (s == 3 * CB - 1);
            if (!last) {
                loadB(s + 1);                 // global prefetch, lands at storeB
                if (row == 2) loadA(s / 3 + 1);
            }
            const int ky = row - 1;
            #pragma unroll
            for (int j = 0; j < 3; ++j) {
                const int kx = j - 1;
                short8 af[4], bf4[4];
                #pragma unroll
                for (int i = 0; i < 4; ++i) {
                    int chunk = aoff[i] + dA[i] * (ky * CW + kx);
                    af[i]  = *(const short8*)&sA[(quad * NCHP + chunk) * 8];
                    bf4[i] = *(const short8*)&sB[((j * 4 + quad) * BN
                                                  + wn * 64 + i * 16 + col) * 8];
                }
                #pragma unroll
                for (int mt = 0; mt < 4; ++mt)
                    #pragma unroll
                    for (int nt = 0; nt < 4; ++nt)
                        acc[mt][nt] = __builtin_amdgcn_mfma_f32_16x16x32_bf16(
                            af[mt], bf4[nt], acc[mt][nt], 0, 0, 0);
            }
            if (!last) {
                __syncthreads();              // all reads of sA/sB done
                storeB();
                if (row == 2) storeA();
                __syncthreads();              // writes visible
            }
        }
    } else {
        // ---- R13's rolled loop (d == 1): A reads/cb 36 -> 18 ----
        short8 AF[3][4];   // rolled A-fragments [kx][mt]
        for (int cb = 0; cb < CB; ++cb) {
            #pragma unroll
            for (int row = 0; row < 3; ++row) {
                const int s = cb * 3 + row;
                const bool last = (s == 3 * CB - 1);
                if (!last) {
                    loadB(s + 1);             // global prefetch, lands at storeB
                    if (row == 2) loadA(cb + 1);
                }
                const int ky = row - 1;
                if (row == 0) {
                    #pragma unroll
                    for (int j = 0; j < 3; ++j)
                        #pragma unroll
                        for (int i = 0; i < 4; ++i)
                            AF[j][i] = *(const short8*)&sA[
                                (quad * NCHP + aoff[i] + (ky * CW + j - 1)) * 8];
                } else {
                    #pragma unroll
                    for (int j = 0; j < 3; ++j) {
                        AF[j][0] = AF[j][1];
                        AF[j][1] = AF[j][2];
                        AF[j][2] = AF[j][3];
                        AF[j][3] = *(const short8*)&sA[
                            (quad * NCHP + aoff[3] + (ky * CW + j - 1)) * 8];
                    }
                }
                #pragma unroll
                for (int j = 0; j < 3; ++j) {
                    short8 bf4[4];
                    #pragma unroll
                    for (int i = 0; i < 4; ++i)
                        bf4[i] = *(const short8*)&sB[((j * 4 + quad) * BN
                                                      + wn * 64 + i * 16 + col) * 8];
                    #pragma unroll
                    for (int mt = 0; mt < 4; ++mt)
                        #pragma unroll
                        for (int nt = 0; nt < 4; ++nt)
                            acc[mt][nt] = __builtin_amdgcn_mfma_f32_16x16x32_bf16(
                                AF[j][mt], bf4[nt], acc[mt][nt], 0, 0, 0);
                }
                if (!last) {
                    __syncthreads();          // all reads of sA/sB done
                    storeB();
                    if (row == 2) storeA();
                    __syncthreads();          // writes visible
                }
            }
        }
    }

    // ---- epilogue ----
    if (FINAL) {
        float* outp = (float*)outv;   // fp32 NCHW direct to d_out
        #pragma unroll
        for (int mt = 0; mt < 4; ++mt) {
            int y = y0 + wm * 4 + mt;
            #pragma unroll
            for (int nt = 0; nt < 4; ++nt) {
                int co = co0 + wn * 64 + nt * 16 + col;
                float bv = bias[co];
                f32x4 vv;
                #pragma unroll
                for (int r2 = 0; r2 < 4; ++r2) {
                    float z = acc[mt][nt][r2] + bv;
                    vv[r2] = z > 0.f ? z : 0.f;
                }
                *(f32x4*)&outp[((size_t)(b * COUT + co) * H + y) * W + x0 + quad * 4] = vv;
            }
        }
    } else if (POOL == 0) {
        ushort* outp = (ushort*)outv;
        #pragma unroll
        for (int mt = 0; mt < 4; ++mt) {
            int y = y0 + wm * 4 + mt;
            #pragma unroll
            for (int nt = 0; nt < 4; ++nt) {
                int co = co0 + wn * 64 + nt * 16 + col;
                float bv = bias[co];
                #pragma unroll
                for (int r2 = 0; r2 < 4; ++r2) {
                    int x = x0 + quad * 4 + r2;
                    float vv = acc[mt][nt][r2] + bv;
                    vv = vv > 0.f ? vv : 0.f;
                    outp[((size_t)(b * H + y) * W + x) * COUT + co] = f2b(vv);
                }
            }
        }
    } else if (POOL == 1) {
        // fused 2x2 maxpool: output is (H/2)x(W/2), NHWC bf16.
        // 2x2 windows are thread-local: rows (wm*4+2*mt2, +1), cols (quad*4+2j, +1).
        ushort* outp = (ushort*)outv;
        #pragma unroll
        for (int nt = 0; nt < 4; ++nt) {
            int co = co0 + wn * 64 + nt * 16 + col;
            float bv = bias[co];
            float v[4][4];
            #pragma unroll
            for (int mt = 0; mt < 4; ++mt)
                #pragma unroll
                for (int r2 = 0; r2 < 4; ++r2) {
                    float z = acc[mt][nt][r2] + bv;
                    v[mt][r2] = z > 0.f ? z : 0.f;
                }
            #pragma unroll
            for (int mt2 = 0; mt2 < 2; ++mt2) {
                int yp = (y0 >> 1) + wm * 2 + mt2;
                #pragma unroll
                for (int j = 0; j < 2; ++j) {
                    int xp = (x0 >> 1) + quad * 2 + j;
                    float m = fmaxf2(fmaxf2(v[2*mt2][2*j],   v[2*mt2][2*j+1]),
                                     fmaxf2(v[2*mt2+1][2*j], v[2*mt2+1][2*j+1]));
                    outp[((size_t)(b * (H/2) + yp) * (W/2) + xp) * COUT + co] = f2b(m);
                }
            }
        }
    } else {
        // POOL == 2: fused irregular pool (mask-gated 2x2 max, replicated).
        ushort* outp = (ushort*)outv;
        int mc[2][2];
        #pragma unroll
        for (int my = 0; my < 2; ++my)
            #pragma unroll
            for (int mx = 0; mx < 2; ++mx) {
                int y = y0 + wm * 4 + my * 2;
                int x = x0 + quad * 4 + mx * 2;
                mc[my][mx] = mask[(b * (H / 2) + (y >> 1)) * (W / 2) + (x >> 1)];
            }
        #pragma unroll
        for (int nt = 0; nt < 4; ++nt) {
            int co = co0 + wn * 64 + nt * 16 + col;
            float bv = bias[co];
            float v[4][4];
            #pragma unroll
            for (int mt = 0; mt < 4; ++mt)
                #pragma unroll
                for (int r2 = 0; r2 < 4; ++r2) {
                    float z = acc[mt][nt][r2] + bv;
                    v[mt][r2] = z > 0.f ? z : 0.f;
                }
            #pragma unroll
            for (int mt = 0; mt < 4; ++mt) {
                int y = y0 + wm * 4 + mt;
                #pragma unroll
                for (int r2 = 0; r2 < 4; ++r2) {
                    int x = x0 + quad * 4 + r2;
                    float p = fmaxf2(fmaxf2(v[mt][r2],     v[mt][r2 ^ 1]),
                                     fmaxf2(v[mt ^ 1][r2], v[mt ^ 1][r2 ^ 1]));
                    float o = mc[mt >> 1][r2 >> 1] ? p : v[mt][r2];
                    outp[((size_t)(b * H + y) * W + x) * COUT + co] = f2b(o);
                }
            }
        }
    }
}

// ---------------------------------------------------------------------------
extern "C" void kernel_launch(void* const* d_in, const int* in_sizes, int n_in,
                              void* d_out, int out_size, void* d_ws, size_t ws_size,
                              hipStream_t stream)
{
    const float* x    = (const float*)d_in[0];
    const int*   mask = (const int*)d_in[1];
    const float* Wt[10];
    const float* bs[10];
    for (int i = 0; i < 10; ++i) {
        Wt[i] = (const float*)d_in[2 + 2 * i];
        bs[i] = (const float*)d_in[3 + 2 * i];
    }

    const size_t ACT = (size_t)4 * 384 * 384 * 64;   // ushorts
    ushort* A  = (ushort*)d_ws;
    ushort* Bb = A + ACT;
    ushort* wpbase = Bb + ACT;

    static const int cins[10]  = {3, 64, 64, 128, 128, 256, 256, 256, 512, 512};
    static const int couts[10] = {64, 64, 128, 128, 256, 256, 256, 512, 512, 512};
    ushort* wp[10];
    size_t wo = 0;
    for (int l = 1; l < 10; ++l) {
        wp[l] = wpbase + wo;
        wo += (size_t)couts[l] * cins[l] * 9;
    }

    RepackArgs ra;
    int off = 0;
    for (int l = 1; l < 10; ++l) {
        ra.w[l - 1]    = Wt[l];
        ra.wp[l - 1]   = wp[l];
        ra.cin[l - 1]  = cins[l];
        ra.cout[l - 1] = couts[l];
        ra.off[l - 1]  = off;
        off += couts[l] * cins[l] * 9;
    }
    ra.off[9] = off;
    repack_all<<<(off + 255) / 256, 256, 0, stream>>>(ra);

    // L1: fp32 NCHW -> bf16 NHWC
    l1_conv<<<dim3(24 * 24, 1, 4), 256, 0, stream>>>(x, Wt[0], bs[0], A);

    // L2: 64->64 @384 (tile 16x16, BN=64), fused maxpool -> 192^2
    conv_mfma<16, 64, 64, 64, 384, 384, false, false, 1>
        <<<dim3(4 * 24 * 24, 1), 256, 0, stream>>>(A, wp[1], bs[1], Bb, nullptr);

    // L3: 64->128 @192 (tile 8x16, BN=128)
    conv_mfma<8, 128, 64, 128, 192, 192, false, false, 0>
        <<<dim3(4 * 24 * 12, 1), 256, 0, stream>>>(Bb, wp[2], bs[2], A, nullptr);
    // L4: 128->128 @192, fused maxpool -> 96^2
    conv_mfma<8, 128, 128, 128, 192, 192, false, false, 1>
        <<<dim3(4 * 24 * 12, 1), 256, 0, stream>>>(A, wp[3], bs[3], Bb, nullptr);

    // L5: 128->256 @96
    conv_mfma<8, 128, 128, 256, 96, 96, false, false, 0>
        <<<dim3(4 * 12 * 6, 2), 256, 0, stream>>>(Bb, wp[4], bs[4], A, nullptr);
    // L6: 256->256
    conv_mfma<8, 128, 256, 256, 96, 96, false, false, 0>
        <<<dim3(4 * 12 * 6, 2), 256, 0, stream>>>(A, wp[5], bs[5], Bb, nullptr);
    // L7: 256->256, fused irregular pool
    conv_mfma<8, 128, 256, 256, 96, 96, false, false, 2>
        <<<dim3(4 * 12 * 6, 2), 256, 0, stream>>>(Bb, wp[6], bs[6], A, mask);

    // L8: gconv 256->512
    conv_mfma<8, 128, 256, 512, 96, 96, true, false, 0>
        <<<dim3(4 * 12 * 6, 4), 256, 0, stream>>>(A, wp[7], bs[7], Bb, mask);
    // L9: gconv 512->512
    conv_mfma<8, 128, 512, 512, 96, 96, true, false, 0>
        <<<dim3(4 * 12 * 6, 4), 256, 0, stream>>>(Bb, wp[8], bs[8], A, mask);
    // L10: gconv 512->512 -> fp32 NCHW d_out
    conv_mfma<8, 128, 512, 512, 96, 96, true, true, 0>
        <<<dim3(4 * 12 * 6, 4), 256, 0, stream>>>(A, wp[9], bs[9], d_out, mask);

    (void)in_sizes; (void)n_in; (void)out_size; (void)ws_size;
}

// Round 12
// 882.998 us; speedup vs baseline: 1.2231x; 1.0623x over previous
//
#include <hip/hip_runtime.h>

// ---------------------------------------------------------------------------
// Round 15 (resubmit — prior bench failed on GPU acquisition, no data).
// R10 verbatim (measured best: 899.7us).
// Session ledger: R10 = conflict-reduced LDS (sA q-plane-major, sB wave-
// linear) + tap-row staged K-loop + epilogue-fused pooling + merged repack.
// Falsified departures: B-from-global (+215us, L2 latency), persistent
// blocks (+117), glds+dbuf (+213, occupancy+barrier drain), XCD swizzle
// (+92, FETCH halved but LDS-pipe-bound), A-register-roll (+38, VGPR
// 104->128 occupancy cost eats the 25% LDS-read saving).
// The K-loop is a narrow optimum: {VGPR 104, 4 blocks/CU, 2-barrier step}.
// ---------------------------------------------------------------------------

typedef __attribute__((ext_vector_type(8))) short short8;
typedef __attribute__((ext_vector_type(4))) float f32x4;

__device__ __forceinline__ float b2f(ushort u) {
    return __uint_as_float(((unsigned)u) << 16);
}
__device__ __forceinline__ ushort f2b(float f) {   // round-to-nearest-even
    unsigned x = __float_as_uint(f);
    x += 0x7FFFu + ((x >> 16) & 1u);
    return (ushort)(x >> 16);
}
__device__ __forceinline__ float fmaxf2(float a, float b) { return a > b ? a : b; }

// ---- repack weights [co][ci][t] f32 -> [t][cb][q][co][ci8] bf16, all layers
struct RepackArgs {
    const float* w[9];
    ushort*      wp[9];
    int cin[9];
    int cout[9];
    int off[10];        // elem-count prefix sums, off[9] = total
};

__global__ __launch_bounds__(256)
void repack_all(RepackArgs a)
{
    int i = blockIdx.x * 256 + threadIdx.x;
    if (i >= a.off[9]) return;
    int l = 0;
    #pragma unroll
    for (int k = 1; k < 9; ++k) l += (i >= a.off[k]);
    int j = i - a.off[l];
    int Cin = a.cin[l], Cout = a.cout[l];
    int CBl  = Cin / 32;
    int c8   = j & 7;
    int co   = (j >> 3) % Cout;          // Cout is a power of two
    int rest = (j >> 3) / Cout;          // = (t*CBl + cb)*4 + q
    int q    = rest & 3;
    int cbt  = rest >> 2;
    int cb   = cbt % CBl;
    int t    = cbt / CBl;
    int ci   = cb * 32 + q * 8 + c8;
    a.wp[l][j] = f2b(a.w[l][((size_t)co * Cin + ci) * 9 + t]);
}

// ------------- L1: 3->64 direct conv, fp32 NCHW in -> bf16 NHWC out ---------
__global__ __launch_bounds__(256)
void l1_conv(const float* __restrict__ in, const float* __restrict__ w,
             const float* __restrict__ bias, ushort* __restrict__ out)
{
    const int H = 384, W = 384;
    __shared__ float s[3][18][18];
    const int tid = threadIdx.x;
    const int tilesX = W / 16;
    const int x0 = (blockIdx.x % tilesX) * 16;
    const int y0 = (blockIdx.x / tilesX) * 16;
    const int b  = blockIdx.z;

    for (int i = tid; i < 3 * 18 * 18; i += 256) {
        int ci = i / (18 * 18);
        int r  = i % (18 * 18);
        int iy = r / 18, ix = r % 18;
        int gy = y0 - 1 + iy, gx = x0 - 1 + ix;
        float v = 0.f;
        if ((unsigned)gy < (unsigned)H && (unsigned)gx < (unsigned)W)
            v = in[((size_t)(b * 3 + ci) * H + gy) * W + gx];
        s[ci][iy][ix] = v;
    }
    __syncthreads();

    const int tx = tid & 15, ty = tid >> 4;
    float iv[3][3][3];
    #pragma unroll
    for (int ci = 0; ci < 3; ++ci)
        #pragma unroll
        for (int ky = 0; ky < 3; ++ky)
            #pragma unroll
            for (int kx = 0; kx < 3; ++kx)
                iv[ci][ky][kx] = s[ci][ty + ky][tx + kx];

    size_t pix = ((size_t)(b * H + y0 + ty) * W + x0 + tx);
    #pragma unroll
    for (int c4 = 0; c4 < 4; ++c4) {
        __align__(16) ushort ob[16];
        #pragma unroll
        for (int co = 0; co < 16; ++co) {
            int coG = c4 * 16 + co;
            float a = bias[coG];
            #pragma unroll
            for (int ci = 0; ci < 3; ++ci)
                #pragma unroll
                for (int ky = 0; ky < 3; ++ky)
                    #pragma unroll
                    for (int kx = 0; kx < 3; ++kx)
                        a = fmaf(w[((size_t)coG * 3 + ci) * 9 + ky * 3 + kx],
                                 iv[ci][ky][kx], a);
            a = a > 0.f ? a : 0.f;
            ob[co] = f2b(a);
        }
        *(short8*)&out[pix * 64 + c4 * 16]     = *(short8*)&ob[0];
        *(short8*)&out[pix * 64 + c4 * 16 + 8] = *(short8*)&ob[8];
    }
}

// ------------- implicit-GEMM conv3x3, tap-row staged, bf16 MFMA -------------
// Block = TRx16 output pixels, 256 threads = 4 waves, wave tile 64x64.
// Per cb: A halo staged once; B staged per tap-ROW with register prefetch of
// next row's B / next cb's A before the MFMA section. Conflict-free LDS
// layouts (sA q-plane-major stride NCH+2; sB [tap][q][co] wave-linear).
// POOL: 0=none, 1=fused 2x2 maxpool (halved output), 2=fused irregular pool.
template<int TR, int BN, int CIN, int COUT, int H, int W, bool GCONV, bool FINAL,
         int POOL>
__global__ __launch_bounds__(256)
void conv_mfma(const ushort* __restrict__ in, const ushort* __restrict__ wp,
               const float* __restrict__ bias, void* __restrict__ outv,
               const int* __restrict__ mask)
{
    constexpr int BM   = TR * 16;
    constexpr int CB   = CIN / 32;
    constexpr int HA   = GCONV ? 2 : 1;
    constexpr int CW   = 16 + 2 * HA;
    constexpr int CR   = TR + 2 * HA;
    constexpr int NCH  = CR * CW;            // A chunks (pixels) per cb
    constexpr int NCHP = NCH + 2;            // q-plane stride (de-alias stores)
    constexpr int WM   = BM / 64;
    constexpr int NSA  = NCH * 4;            // 16B units to stage for A
    constexpr int NSLA = (NSA + 255) / 256;
    constexpr int NSB  = 12 * BN;            // 16B units per tap-row of B
    constexpr int NSLB = NSB / 256;
    static_assert(NSB % 256 == 0, "B staging must tile 256 threads");

    __shared__ __align__(16) ushort sA[4 * NCHP * 8];
    __shared__ __align__(16) ushort sB[12 * BN * 8];

    const int tid  = threadIdx.x;
    const int lane = tid & 63;
    const int wv   = tid >> 6;
    const int wm   = wv % WM;
    const int wn   = wv / WM;
    const int col  = lane & 15;
    const int quad = lane >> 4;

    const int tiles_x = W / 16, tiles_y = H / TR;
    int sp = blockIdx.x;
    const int b  = sp / (tiles_x * tiles_y);
    int rr = sp - b * tiles_x * tiles_y;
    const int ty = rr / tiles_x;
    const int tx = rr - ty * tiles_x;
    const int y0 = ty * TR, x0 = tx * 16;
    const int co0 = blockIdx.y * BN;

    int dA[4], aoff[4];
    #pragma unroll
    for (int mt = 0; mt < 4; ++mt) {
        dA[mt] = 1;
        if (GCONV) {
            int y = y0 + wm * 4 + mt, x = x0 + col;
            dA[mt] = mask[(b * (H / 2) + (y >> 1)) * (W / 2) + (x >> 1)] ? 2 : 1;
        }
        aoff[mt] = (HA + wm * 4 + mt) * CW + HA + col;
    }

    short8 pA[NSLA];
    short8 pB[NSLB];

    auto loadA = [&](int cb) {
        #pragma unroll
        for (int k = 0; k < NSLA; ++k) {
            int i = tid + k * 256;
            short8 v = {0, 0, 0, 0, 0, 0, 0, 0};
            if (NSA == NSLA * 256 || i < NSA) {
                int chunk = i >> 2, part = i & 3;     // coalesced: 64B / 4 lanes
                int yy = chunk / CW, xx = chunk - yy * CW;
                int gy = y0 - HA + yy, gx = x0 - HA + xx;
                if ((unsigned)gy < (unsigned)H && (unsigned)gx < (unsigned)W)
                    v = *(const short8*)(in + ((size_t)(b * H + gy) * W + gx) * CIN
                                         + cb * 32 + part * 8);
            }
            pA[k] = v;
        }
    };
    auto storeA = [&]() {
        #pragma unroll
        for (int k = 0; k < NSLA; ++k) {
            int i = tid + k * 256;
            if (NSA == NSLA * 256 || i < NSA) {
                int chunk = i >> 2, part = i & 3;
                *(short8*)&sA[(part * NCHP + chunk) * 8] = pA[k];
            }
        }
    };
    auto loadB = [&](int s) {
        int cb = s / 3, row = s % 3;
        #pragma unroll
        for (int k = 0; k < NSLB; ++k) {
            int i = tid + k * 256;
            int co = i % BN;
            int rq = i / BN;                     // tl*4 + q
            const ushort* gp = wp
                + (((size_t)(row * 3 + (rq >> 2)) * CB + cb) * 4 + (rq & 3))
                      * COUT * 8
                + (size_t)(co0 + co) * 8;
            pB[k] = *(const short8*)gp;          // wave reads 1KB contiguous
        }
    };
    auto storeB = [&]() {
        #pragma unroll
        for (int k = 0; k < NSLB; ++k) {
            int i = tid + k * 256;
            *(short8*)&sB[(size_t)i * 8] = pB[k];    // wave-linear, 0 conflicts
        }
    };

    f32x4 acc[4][4];
    #pragma unroll
    for (int i = 0; i < 4; ++i)
        #pragma unroll
        for (int j = 0; j < 4; ++j)
            acc[i][j] = (f32x4){0.f, 0.f, 0.f, 0.f};

    // prologue
    loadA(0);
    loadB(0);
    storeA();
    storeB();
    __syncthreads();

    for (int s = 0; s < 3 * CB; ++s) {
        const int row  = s % 3;
        const bool last = (s == 3 * CB - 1);
        if (!last) {
            loadB(s + 1);                 // global prefetch, lands at storeB
            if (row == 2) loadA(s / 3 + 1);
        }
        const int ky = row - 1;
        #pragma unroll
        for (int j = 0; j < 3; ++j) {
            const int kx = j - 1;
            short8 af[4], bf4[4];
            #pragma unroll
            for (int i = 0; i < 4; ++i) {
                int chunk = aoff[i] + dA[i] * (ky * CW + kx);
                af[i]  = *(const short8*)&sA[(quad * NCHP + chunk) * 8];
                bf4[i] = *(const short8*)&sB[((j * 4 + quad) * BN
                                              + wn * 64 + i * 16 + col) * 8];
            }
            #pragma unroll
            for (int mt = 0; mt < 4; ++mt)
                #pragma unroll
                for (int nt = 0; nt < 4; ++nt)
                    acc[mt][nt] = __builtin_amdgcn_mfma_f32_16x16x32_bf16(
                        af[mt], bf4[nt], acc[mt][nt], 0, 0, 0);
        }
        if (!last) {
            __syncthreads();              // all reads of sA/sB done
            storeB();
            if (row == 2) storeA();
            __syncthreads();              // writes visible
        }
    }

    // ---- epilogue ----
    if (FINAL) {
        float* outp = (float*)outv;   // fp32 NCHW direct to d_out
        #pragma unroll
        for (int mt = 0; mt < 4; ++mt) {
            int y = y0 + wm * 4 + mt;
            #pragma unroll
            for (int nt = 0; nt < 4; ++nt) {
                int co = co0 + wn * 64 + nt * 16 + col;
                float bv = bias[co];
                f32x4 vv;
                #pragma unroll
                for (int r2 = 0; r2 < 4; ++r2) {
                    float z = acc[mt][nt][r2] + bv;
                    vv[r2] = z > 0.f ? z : 0.f;
                }
                *(f32x4*)&outp[((size_t)(b * COUT + co) * H + y) * W + x0 + quad * 4] = vv;
            }
        }
    } else if (POOL == 0) {
        ushort* outp = (ushort*)outv;
        #pragma unroll
        for (int mt = 0; mt < 4; ++mt) {
            int y = y0 + wm * 4 + mt;
            #pragma unroll
            for (int nt = 0; nt < 4; ++nt) {
                int co = co0 + wn * 64 + nt * 16 + col;
                float bv = bias[co];
                #pragma unroll
                for (int r2 = 0; r2 < 4; ++r2) {
                    int x = x0 + quad * 4 + r2;
                    float vv = acc[mt][nt][r2] + bv;
                    vv = vv > 0.f ? vv : 0.f;
                    outp[((size_t)(b * H + y) * W + x) * COUT + co] = f2b(vv);
                }
            }
        }
    } else if (POOL == 1) {
        // fused 2x2 maxpool: output is (H/2)x(W/2), NHWC bf16.
        // 2x2 windows are thread-local: rows (wm*4+2*mt2, +1), cols (quad*4+2j, +1).
        ushort* outp = (ushort*)outv;
        #pragma unroll
        for (int nt = 0; nt < 4; ++nt) {
            int co = co0 + wn * 64 + nt * 16 + col;
            float bv = bias[co];
            float v[4][4];
            #pragma unroll
            for (int mt = 0; mt < 4; ++mt)
                #pragma unroll
                for (int r2 = 0; r2 < 4; ++r2) {
                    float z = acc[mt][nt][r2] + bv;
                    v[mt][r2] = z > 0.f ? z : 0.f;
                }
            #pragma unroll
            for (int mt2 = 0; mt2 < 2; ++mt2) {
                int yp = (y0 >> 1) + wm * 2 + mt2;
                #pragma unroll
                for (int j = 0; j < 2; ++j) {
                    int xp = (x0 >> 1) + quad * 2 + j;
                    float m = fmaxf2(fmaxf2(v[2*mt2][2*j],   v[2*mt2][2*j+1]),
                                     fmaxf2(v[2*mt2+1][2*j], v[2*mt2+1][2*j+1]));
                    outp[((size_t)(b * (H/2) + yp) * (W/2) + xp) * COUT + co] = f2b(m);
                }
            }
        }
    } else {
        // POOL == 2: fused irregular pool (mask-gated 2x2 max, replicated).
        ushort* outp = (ushort*)outv;
        int mc[2][2];
        #pragma unroll
        for (int my = 0; my < 2; ++my)
            #pragma unroll
            for (int mx = 0; mx < 2; ++mx) {
                int y = y0 + wm * 4 + my * 2;
                int x = x0 + quad * 4 + mx * 2;
                mc[my][mx] = mask[(b * (H / 2) + (y >> 1)) * (W / 2) + (x >> 1)];
            }
        #pragma unroll
        for (int nt = 0; nt < 4; ++nt) {
            int co = co0 + wn * 64 + nt * 16 + col;
            float bv = bias[co];
            float v[4][4];
            #pragma unroll
            for (int mt = 0; mt < 4; ++mt)
                #pragma unroll
                for (int r2 = 0; r2 < 4; ++r2) {
                    float z = acc[mt][nt][r2] + bv;
                    v[mt][r2] = z > 0.f ? z : 0.f;
                }
            #pragma unroll
            for (int mt = 0; mt < 4; ++mt) {
                int y = y0 + wm * 4 + mt;
                #pragma unroll
                for (int r2 = 0; r2 < 4; ++r2) {
                    int x = x0 + quad * 4 + r2;
                    float p = fmaxf2(fmaxf2(v[mt][r2],     v[mt][r2 ^ 1]),
                                     fmaxf2(v[mt ^ 1][r2], v[mt ^ 1][r2 ^ 1]));
                    float o = mc[mt >> 1][r2 >> 1] ? p : v[mt][r2];
                    outp[((size_t)(b * H + y) * W + x) * COUT + co] = f2b(o);
                }
            }
        }
    }
}

// ---------------------------------------------------------------------------
extern "C" void kernel_launch(void* const* d_in, const int* in_sizes, int n_in,
                              void* d_out, int out_size, void* d_ws, size_t ws_size,
                              hipStream_t stream)
{
    const float* x    = (const float*)d_in[0];
    const int*   mask = (const int*)d_in[1];
    const float* Wt[10];
    const float* bs[10];
    for (int i = 0; i < 10; ++i) {
        Wt[i] = (const float*)d_in[2 + 2 * i];
        bs[i] = (const float*)d_in[3 + 2 * i];
    }

    const size_t ACT = (size_t)4 * 384 * 384 * 64;   // ushorts
    ushort* A  = (ushort*)d_ws;
    ushort* Bb = A + ACT;
    ushort* wpbase = Bb + ACT;

    static const int cins[10]  = {3, 64, 64, 128, 128, 256, 256, 256, 512, 512};
    static const int couts[10] = {64, 64, 128, 128, 256, 256, 256, 512, 512, 512};
    ushort* wp[10];
    size_t wo = 0;
    for (int l = 1; l < 10; ++l) {
        wp[l] = wpbase + wo;
        wo += (size_t)couts[l] * cins[l] * 9;
    }

    RepackArgs ra;
    int off = 0;
    for (int l = 1; l < 10; ++l) {
        ra.w[l - 1]    = Wt[l];
        ra.wp[l - 1]   = wp[l];
        ra.cin[l - 1]  = cins[l];
        ra.cout[l - 1] = couts[l];
        ra.off[l - 1]  = off;
        off += couts[l] * cins[l] * 9;
    }
    ra.off[9] = off;
    repack_all<<<(off + 255) / 256, 256, 0, stream>>>(ra);

    // L1: fp32 NCHW -> bf16 NHWC
    l1_conv<<<dim3(24 * 24, 1, 4), 256, 0, stream>>>(x, Wt[0], bs[0], A);

    // L2: 64->64 @384 (tile 16x16, BN=64), fused maxpool -> 192^2
    conv_mfma<16, 64, 64, 64, 384, 384, false, false, 1>
        <<<dim3(4 * 24 * 24, 1), 256, 0, stream>>>(A, wp[1], bs[1], Bb, nullptr);

    // L3: 64->128 @192 (tile 8x16, BN=128)
    conv_mfma<8, 128, 64, 128, 192, 192, false, false, 0>
        <<<dim3(4 * 24 * 12, 1), 256, 0, stream>>>(Bb, wp[2], bs[2], A, nullptr);
    // L4: 128->128 @192, fused maxpool -> 96^2
    conv_mfma<8, 128, 128, 128, 192, 192, false, false, 1>
        <<<dim3(4 * 24 * 12, 1), 256, 0, stream>>>(A, wp[3], bs[3], Bb, nullptr);

    // L5: 128->256 @96
    conv_mfma<8, 128, 128, 256, 96, 96, false, false, 0>
        <<<dim3(4 * 12 * 6, 2), 256, 0, stream>>>(Bb, wp[4], bs[4], A, nullptr);
    // L6: 256->256
    conv_mfma<8, 128, 256, 256, 96, 96, false, false, 0>
        <<<dim3(4 * 12 * 6, 2), 256, 0, stream>>>(A, wp[5], bs[5], Bb, nullptr);
    // L7: 256->256, fused irregular pool
    conv_mfma<8, 128, 256, 256, 96, 96, false, false, 2>
        <<<dim3(4 * 12 * 6, 2), 256, 0, stream>>>(Bb, wp[6], bs[6], A, mask);

    // L8: gconv 256->512
    conv_mfma<8, 128, 256, 512, 96, 96, true, false, 0>
        <<<dim3(4 * 12 * 6, 4), 256, 0, stream>>>(A, wp[7], bs[7], Bb, mask);
    // L9: gconv 512->512
    conv_mfma<8, 128, 512, 512, 96, 96, true, false, 0>
        <<<dim3(4 * 12 * 6, 4), 256, 0, stream>>>(Bb, wp[8], bs[8], A, mask);
    // L10: gconv 512->512 -> fp32 NCHW d_out
    conv_mfma<8, 128, 512, 512, 96, 96, true, true, 0>
        <<<dim3(4 * 12 * 6, 4), 256, 0, stream>>>(A, wp[9], bs[9], d_out, mask);

    (void)in_sizes; (void)n_in; (void)out_size; (void)ws_size;
}